// Round 1
// 177.912 us; speedup vs baseline: 1.0017x; 1.0017x over previous
//
#include <hip/hip_runtime.h>
#include <hip/hip_bf16.h>

#define N_NODES 20000
#define N_EDGES 640000
#define HIDDEN 256
#define HEADS 8
#define HEAD_DIM 32
#define N_FEATS 9
#define VOCAB 119

typedef __hip_bfloat16 bf16;
typedef __attribute__((ext_vector_type(8))) short short8;
typedef __attribute__((ext_vector_type(4))) float f32x4;
typedef __attribute__((ext_vector_type(2))) float f32x2;

__device__ __forceinline__ ushort f2u(float x) { union { ushort u; bf16 b; } c; c.b = __float2bfloat16(x); return c.u; }

// packed f32 math (CDNA: full-rate 2x FMA per instr)
__device__ __forceinline__ f32x2 pk_fma(f32x2 a, f32x2 b, f32x2 c) {
    f32x2 d;
    asm("v_pk_fma_f32 %0, %1, %2, %3" : "=v"(d) : "v"(a), "v"(b), "v"(c));
    return d;
}
__device__ __forceinline__ f32x2 pk_add(f32x2 a, f32x2 b) {
    f32x2 d;
    asm("v_pk_add_f32 %0, %1, %2" : "=v"(d) : "v"(a), "v"(b));
    return d;
}

// DPP cross-lane fetch (VALU pipe, no ds_bpermute latency).
// 0xB1 = quad_perm[1,0,3,2] (xor 1), 0x4E = quad_perm[2,3,0,1] (xor 2),
// 0x128 = row_ror:8 (xor 8 within a 16-lane row).
template <int CTRL>
__device__ __forceinline__ float dpp_xor(float v) {
    return __int_as_float(__builtin_amdgcn_update_dpp(
        0, __float_as_int(v), CTRL, 0xf, 0xf, true));
}

__device__ __forceinline__ float fast_exp2(float x) {
#if __has_builtin(__builtin_amdgcn_exp2f)
    return __builtin_amdgcn_exp2f(x);
#else
    return exp2f(x);
#endif
}

// 2-way bf16 dot with f32 accumulate: 1 VALU instr, operands already packed.
#if __has_builtin(__builtin_amdgcn_fdot2_f32_bf16)
typedef __attribute__((ext_vector_type(2))) __bf16 bf16x2_t;
__device__ __forceinline__ float dot2bf(uint a, uint b, float c) {
    return __builtin_amdgcn_fdot2_f32_bf16(__builtin_bit_cast(bf16x2_t, a),
                                           __builtin_bit_cast(bf16x2_t, b), c, false);
}
#else
__device__ __forceinline__ float dot2bf(uint a, uint b, float c) {
    return c + __uint_as_float(a << 16) * __uint_as_float(b << 16)
             + __uint_as_float(a & 0xffff0000u) * __uint_as_float(b & 0xffff0000u);
}
#endif

// ---------------------------------------------------------------- fused pre-work
// blocks [0,5000): encode  (h[n][t] = sum_f emb[f][X[n,f]][t], bf16 out)
// blocks [5000,6027): weight fp32->bf16 (concat qkv) + bias concat
// blocks [6027,6106): row_ptr by binary search
__global__ void k_pre(const int* __restrict__ X, const float* __restrict__ emb,
                      bf16* __restrict__ h,
                      const float* __restrict__ qw, const float* __restrict__ kw,
                      const float* __restrict__ vw, const float* __restrict__ ow,
                      const float* __restrict__ qb, const float* __restrict__ kb,
                      const float* __restrict__ vb,
                      bf16* __restrict__ wqkv, bf16* __restrict__ wo,
                      float* __restrict__ qkvb,
                      const int* __restrict__ erow, int* __restrict__ row_ptr) {
    int b = blockIdx.x;
    if (b < 5000) {
        int tid = b * 256 + threadIdx.x;
        int n = tid >> 6;
        int c4 = (tid & 63) * 4;
        float4 a = make_float4(0.f, 0.f, 0.f, 0.f);
#pragma unroll
        for (int f = 0; f < N_FEATS; ++f) {
            int idx = X[n * N_FEATS + f];
            float4 e = *(const float4*)(emb + ((size_t)(f * VOCAB + idx)) * HIDDEN + c4);
            a.x += e.x; a.y += e.y; a.z += e.z; a.w += e.w;
        }
        ushort4 o = make_ushort4(f2u(a.x), f2u(a.y), f2u(a.z), f2u(a.w));
        *(ushort4*)((ushort*)h + (size_t)n * HIDDEN + c4) = o;
    } else if (b < 6027) {
        int i = (b - 5000) * 256 + threadIdx.x;     // 262912 total
        if (i < 196608) {
            const float* s = i < 65536 ? qw : i < 131072 ? kw : vw;
            wqkv[i] = __float2bfloat16(s[i & 65535]);
        } else if (i < 262144) {
            wo[i - 196608] = __float2bfloat16(ow[i - 196608]);
        } else if (i < 262912) {
            int j = i - 262144;                      // 768 bias elems
            const float* s = j < 256 ? qb : j < 512 ? kb : vb;
            qkvb[j] = s[j & 255];
        }
    } else {
        int n = (b - 6027) * 256 + threadIdx.x;
        if (n > N_NODES) return;
        int lo = 0, hi = N_EDGES;
        while (lo < hi) {
            int mid = (lo + hi) >> 1;
            if (erow[mid] < n) lo = mid + 1; else hi = mid;
        }
        row_ptr[n] = lo;
    }
}

// ---------------------------------------------------------------- MFMA GEMM core
// (R10 structure: LDS-staged A+B, register prefetch, 2 barriers/K-iter.)
// MODE 0: qkv -> head-pair-sliced layouts  qhp[hp][n][64], kvhp[hp][n][128]
// MODE 1: float out [n][256]
// GUARD: per-element n bounds checks (only the last x-block needs them)
// TM: row-tile (128 or 64). Cols always 128.
template <int MODE, bool GUARD, int TM>
__device__ __forceinline__ void gemm_core(const bf16* __restrict__ A,
                                          const bf16* __restrict__ W,
                                          const float* __restrict__ bias,
                                          void* __restrict__ Y0, void* __restrict__ Y1,
                                          float s_q, int n0, int d0) {
    constexpr int RI = TM / 32;          // row subtiles per wave (4 or 2)
    __shared__ short As[TM * 72];
    __shared__ short Bs[128 * 72];
    int t = threadIdx.x;
    int lane = t & 63, w = t >> 6;
    int wr = (w >> 1) * (TM / 2), wc = (w & 1) * 64;
    int lr = lane & 15, quad = lane >> 4;

    f32x4 acc[RI][4] = {};
    short8 ra[RI], rb[4];
    int srowA[RI], skoA[RI], srowB[4], skoB[4];
#pragma unroll
    for (int it = 0; it < RI; ++it) { int c = t + 256 * it; srowA[it] = c >> 3; skoA[it] = (c & 7) * 8; }
#pragma unroll
    for (int it = 0; it < 4; ++it) { int c = t + 256 * it; srowB[it] = c >> 3; skoB[it] = (c & 7) * 8; }

    // prologue: load k0=0, stage to LDS
#pragma unroll
    for (int it = 0; it < RI; ++it) {
        int n = n0 + srowA[it];
        short8 av = {};
        if (!GUARD || n < N_NODES) av = *(const short8*)(A + (size_t)n * HIDDEN + skoA[it]);
        ra[it] = av;
    }
#pragma unroll
    for (int it = 0; it < 4; ++it)
        rb[it] = *(const short8*)(W + (size_t)(d0 + srowB[it]) * HIDDEN + skoB[it]);
#pragma unroll
    for (int it = 0; it < RI; ++it) *(short8*)(&As[srowA[it] * 72 + skoA[it]]) = ra[it];
#pragma unroll
    for (int it = 0; it < 4; ++it)  *(short8*)(&Bs[srowB[it] * 72 + skoB[it]]) = rb[it];
    __syncthreads();

    for (int k0 = 64; k0 < 256; k0 += 64) {
        // prefetch next K-slab into regs (overlaps with MFMA below)
#pragma unroll
        for (int it = 0; it < RI; ++it) {
            int n = n0 + srowA[it];
            short8 av = {};
            if (!GUARD || n < N_NODES) av = *(const short8*)(A + (size_t)n * HIDDEN + k0 + skoA[it]);
            ra[it] = av;
        }
#pragma unroll
        for (int it = 0; it < 4; ++it)
            rb[it] = *(const short8*)(W + (size_t)(d0 + srowB[it]) * HIDDEN + k0 + skoB[it]);
        {
            short8 af[RI][2], bfr[4][2];
#pragma unroll
            for (int i = 0; i < RI; ++i)
#pragma unroll
                for (int kk = 0; kk < 2; ++kk)
                    af[i][kk] = *(short8*)(&As[(wr + i * 16 + lr) * 72 + kk * 32 + quad * 8]);
#pragma unroll
            for (int j = 0; j < 4; ++j)
#pragma unroll
                for (int kk = 0; kk < 2; ++kk)
                    bfr[j][kk] = *(short8*)(&Bs[(wc + j * 16 + lr) * 72 + kk * 32 + quad * 8]);
#pragma unroll
            for (int kk = 0; kk < 2; ++kk)
#pragma unroll
                for (int i = 0; i < RI; ++i)
#pragma unroll
                    for (int j = 0; j < 4; ++j)
                        acc[i][j] = __builtin_amdgcn_mfma_f32_16x16x32_bf16(
                            af[i][kk], bfr[j][kk], acc[i][j], 0, 0, 0);
        }
        __syncthreads();
#pragma unroll
        for (int it = 0; it < RI; ++it) *(short8*)(&As[srowA[it] * 72 + skoA[it]]) = ra[it];
#pragma unroll
        for (int it = 0; it < 4; ++it)  *(short8*)(&Bs[srowB[it] * 72 + skoB[it]]) = rb[it];
        __syncthreads();
    }
    // last compute
    {
        short8 af[RI][2], bfr[4][2];
#pragma unroll
        for (int i = 0; i < RI; ++i)
#pragma unroll
            for (int kk = 0; kk < 2; ++kk)
                af[i][kk] = *(short8*)(&As[(wr + i * 16 + lr) * 72 + kk * 32 + quad * 8]);
#pragma unroll
        for (int j = 0; j < 4; ++j)
#pragma unroll
            for (int kk = 0; kk < 2; ++kk)
                bfr[j][kk] = *(short8*)(&Bs[(wc + j * 16 + lr) * 72 + kk * 32 + quad * 8]);
#pragma unroll
        for (int kk = 0; kk < 2; ++kk)
#pragma unroll
            for (int i = 0; i < RI; ++i)
#pragma unroll
                for (int j = 0; j < 4; ++j)
                    acc[i][j] = __builtin_amdgcn_mfma_f32_16x16x32_bf16(
                        af[i][kk], bfr[j][kk], acc[i][j], 0, 0, 0);
    }

    // epilogue: C/D layout col=lane&15, row=quad*4+reg
    // target selection is UNIFORM per j (dbase has no lane term) -> scalar branches
#pragma unroll
    for (int j = 0; j < 4; ++j) {
        int dbase = d0 + wc + j * 16;          // uniform
        float bj = bias[dbase + lr];
        if constexpr (MODE == 0) {
            float sc = (dbase < 256) ? s_q : 1.f;
            ushort* dst; int stride;
            if (dbase < 256) {
                dst = (ushort*)Y0 + (size_t)(dbase >> 6) * N_NODES * 64 + (dbase & 63) + lr;
                stride = 64;
            } else if (dbase < 512) {
                int e = dbase - 256;
                dst = (ushort*)Y1 + (size_t)(e >> 6) * N_NODES * 128 + (e & 63) + lr;
                stride = 128;
            } else {
                int e = dbase - 512;
                dst = (ushort*)Y1 + (size_t)(e >> 6) * N_NODES * 128 + 64 + (e & 63) + lr;
                stride = 128;
            }
#pragma unroll
            for (int i = 0; i < RI; ++i)
#pragma unroll
                for (int r = 0; r < 4; ++r) {
                    int n = n0 + wr + i * 16 + quad * 4 + r;
                    if (GUARD && n >= N_NODES) continue;
                    dst[(size_t)n * stride] = f2u((acc[i][j][r] + bj) * sc);
                }
        } else {
            float* dst = (float*)Y0 + dbase + lr;
#pragma unroll
            for (int i = 0; i < RI; ++i)
#pragma unroll
                for (int r = 0; r < 4; ++r) {
                    int n = n0 + wr + i * 16 + quad * 4 + r;
                    if (GUARD && n >= N_NODES) continue;
                    dst[(size_t)n * HIDDEN] = acc[i][j][r] + bj;
                }
        }
    }
}

__global__ __launch_bounds__(256, 2) void k_gemm_qkv(
    const bf16* __restrict__ A, const bf16* __restrict__ wqkv,
    const float* __restrict__ qkvb, ushort* __restrict__ qhp,
    ushort* __restrict__ kvhp, float qscale) {
    int n0 = blockIdx.x * 128;
    if (n0 + 128 <= N_NODES)
        gemm_core<0, false, 128>(A, wqkv, qkvb, qhp, kvhp, qscale, n0, blockIdx.y * 128);
    else
        gemm_core<0, true, 128>(A, wqkv, qkvb, qhp, kvhp, qscale, n0, blockIdx.y * 128);
}

// TM=64: 626 blocks (2.4/CU), 27 KB LDS, 4 blocks/CU occupancy target
__global__ __launch_bounds__(256, 4) void k_gemm_o(
    const bf16* __restrict__ A, const bf16* __restrict__ W,
    const float* __restrict__ bias, float* __restrict__ Y) {
    int n0 = blockIdx.x * 64;
    if (n0 + 64 <= N_NODES)
        gemm_core<1, false, 64>(A, W, bias, Y, nullptr, 1.f, n0, blockIdx.y * 128);
    else
        gemm_core<1, true, 64>(A, W, bias, Y, nullptr, 1.f, n0, blockIdx.y * 128);
}

// ---------------------------------------------------------------- fused attention
// Head-pair partitioned (XCD-local kv) + zero-waste lanes + packed bf16 dot +
// distance-2 software pipeline with NAMED register buffers.
// R14 changes (VALU-bound at 74%, 0 bank conflicts, HBM 27%):
//  - v_pk_fma_f32 PV accumulate (4 packed FMAs instead of 8 scalar)
//  - exp2 with log2e folded into qscale at GEMM time (v_exp only, no mul)
//  - score reduce via DPP quad_perm (VALU) instead of ds_bpermute shfl
//  - reduce-scatter final combine (~31 instrs vs 54 butterfly); each lane
//    ends owning exactly one of the 64 dims -> per-lane ushort store
//  - odd-tail split: no fully-masked dead compute block, no dead prefetch
//    on the final pair (uniform branch)
__global__ __launch_bounds__(256) void k_attn(
    const int* __restrict__ row_ptr, const int* __restrict__ col,
    const ushort* __restrict__ qhp, const ushort* __restrict__ kvhp,
    bf16* __restrict__ agg) {
    int b = blockIdx.x;
    int x = b & 7;
    int hp = x & 3;
    int wave = threadIdx.x >> 6;
    int n = (b >> 3) * 8 + (x >> 2) * 4 + wave;
    int lane = threadIdx.x & 63;
    int my = lane >> 3;          // edge slot 0..7
    int d8 = lane & 7;           // dim slot (head = d8>>2)

    int start = row_ptr[n];
    int deg = row_ptr[n + 1] - start;

    ushort* orow = (ushort*)agg + (size_t)n * HIDDEN + hp * 64;
    if (deg == 0) {
        if (lane < 8) { uint4 zo = {}; *(uint4*)(orow + lane * 8) = zo; }
        return;
    }

    const ushort* qrow = qhp + ((size_t)hp * N_NODES + n) * 64;
    uint4 qu = *(const uint4*)(qrow + d8 * 8);   // packed bf16 pairs (pre-scaled by log2e)

    const ushort* kvbase = kvhp + (size_t)hp * N_NODES * 128;
    const int* cb = col + start;
    int degm = deg - my;                         // mask: it*8 < degm  (uniform LHS)

    float z = 0.f;
    f32x2 av0 = {0.f, 0.f}, av1 = {0.f, 0.f}, av2v = {0.f, 0.f}, av3 = {0.f, 0.f};

#define ATTN_COMPUTE(K, V, IT8) do {                                                      \
        float sa_ = dot2bf((K).x, qu.x, 0.f);                                             \
        float sb_ = dot2bf((K).y, qu.y, 0.f);                                             \
        sa_ = dot2bf((K).z, qu.z, sa_);                                                   \
        sb_ = dot2bf((K).w, qu.w, sb_);                                                   \
        float s_ = sa_ + sb_;                                                             \
        s_ += dpp_xor<0xB1>(s_);                                                          \
        s_ += dpp_xor<0x4E>(s_);                                                          \
        float p_ = ((IT8) < degm) ? fast_exp2(s_) : 0.f;                                  \
        z += p_;                                                                          \
        f32x2 pp_; pp_.x = p_; pp_.y = p_;                                                \
        f32x2 vf0_, vf1_, vf2_, vf3_;                                                     \
        vf0_.x = __uint_as_float((V).x << 16); vf0_.y = __uint_as_float((V).x & 0xffff0000u); \
        vf1_.x = __uint_as_float((V).y << 16); vf1_.y = __uint_as_float((V).y & 0xffff0000u); \
        vf2_.x = __uint_as_float((V).z << 16); vf2_.y = __uint_as_float((V).z & 0xffff0000u); \
        vf3_.x = __uint_as_float((V).w << 16); vf3_.y = __uint_as_float((V).w & 0xffff0000u); \
        av0  = pk_fma(vf0_, pp_, av0);                                                    \
        av1  = pk_fma(vf1_, pp_, av1);                                                    \
        av2v = pk_fma(vf2_, pp_, av2v);                                                   \
        av3  = pk_fma(vf3_, pp_, av3);                                                    \
    } while (0)

    if (deg <= 64) {                      // deg ~ Poisson(32): nearly always
        int c_all = cb[min(lane, deg - 1)];
        int nb = (deg + 7) >> 3;          // 1..8 iterations of 8 edges
        int np = nb >> 1;                 // full pairs

        // prologue: iters 0 and 1 (wrapped -> always-valid cols)
        int c0 = __shfl(c_all, my);
        int c1 = __shfl(c_all, (8 + my) & 63);
        uint o0 = ((uint)c0 << 7) + (uint)d8 * 8;
        uint o1 = ((uint)c1 << 7) + (uint)d8 * 8;
        uint4 ka  = *(const uint4*)(kvbase + o0), va  = *(const uint4*)(kvbase + o0 + 64);
        uint4 kb2 = *(const uint4*)(kvbase + o1), vb2 = *(const uint4*)(kvbase + o1 + 64);

#pragma unroll 1
        for (int pit = 0; pit < np; ++pit) {
            int it = pit * 2;
            uint4 kn0, vn0, kn1, vn1;
            bool pf = (pit + 1 < np) || (nb & 1);   // uniform: prefetch needed?
            if (pf) {
                int cn0 = __shfl(c_all, ((it + 2) * 8 + my) & 63);
                int cn1 = __shfl(c_all, ((it + 3) * 8 + my) & 63);
                uint on0 = ((uint)cn0 << 7) + (uint)d8 * 8;
                uint on1 = ((uint)cn1 << 7) + (uint)d8 * 8;
                kn0 = *(const uint4*)(kvbase + on0); vn0 = *(const uint4*)(kvbase + on0 + 64);
                kn1 = *(const uint4*)(kvbase + on1); vn1 = *(const uint4*)(kvbase + on1 + 64);
            }
            ATTN_COMPUTE(ka, va, it * 8);
            ATTN_COMPUTE(kb2, vb2, it * 8 + 8);
            if (pf) { ka = kn0; va = vn0; kb2 = kn1; vb2 = vn1; }
        }
        if (nb & 1)                        // odd tail: single masked iteration
            ATTN_COMPUTE(ka, va, (nb - 1) * 8);
    } else {
        for (int i = 0; i < deg; i += 8) {
            int idx = i + my;
            int cidx = idx < deg ? idx : deg - 1;
            int c = cb[cidx];
            uint off = ((uint)c << 7) + (uint)d8 * 8;
            uint4 ku = *(const uint4*)(kvbase + off);
            uint4 vu = *(const uint4*)(kvbase + off + 64);
            ATTN_COMPUTE(ku, vu, i);
        }
    }
#undef ATTN_COMPUTE

    // z: full butterfly over the 8 edge slots (per-lane z is for head d8>>2)
    z += dpp_xor<0x128>(z);          // xor 8 (row_ror:8, VALU)
    z += __shfl_xor(z, 16);
    z += __shfl_xor(z, 32);

    // av: reduce-scatter over slot bits 3..5. Lane keeps the half matching its
    // bit; sends the other half; final dim = d8*8 + b3*4 + b4*2 + b5.
    bool b3 = (lane & 8) != 0, b4 = (lane & 16) != 0, b5 = (lane & 32) != 0;
    // stage 1 (xor 8, via DPP)
    f32x2 sd0 = b3 ? av0 : av2v;     // the half I do NOT keep
    f32x2 sd1 = b3 ? av1 : av3;
    f32x2 r0, r1;
    r0.x = dpp_xor<0x128>(sd0.x); r0.y = dpp_xor<0x128>(sd0.y);
    r1.x = dpp_xor<0x128>(sd1.x); r1.y = dpp_xor<0x128>(sd1.y);
    f32x2 t0 = pk_add(b3 ? av2v : av0, r0);   // kept rel dims {b3*4+0, +1}
    f32x2 t1 = pk_add(b3 ? av3  : av1, r1);   // kept rel dims {b3*4+2, +3}
    // stage 2 (xor 16)
    f32x2 sdu = b4 ? t0 : t1;
    f32x2 ru; ru.x = __shfl_xor(sdu.x, 16); ru.y = __shfl_xor(sdu.y, 16);
    f32x2 u = pk_add(b4 ? t1 : t0, ru);       // kept rel dims {b3*4+b4*2+0, +1}
    // stage 3 (xor 32)
    float sw = b5 ? u.x : u.y;
    float rw = __shfl_xor(sw, 32);
    float w = (b5 ? u.y : u.x) + rw;          // total for my dim

    int dim = d8 * 8 + ((lane >> 3) & 1) * 4 + ((lane >> 4) & 1) * 2 + ((lane >> 5) & 1);
    float invz = 1.f / z;
    orow[dim] = f2u(w * invz);
}

// ---------------------------------------------------------------- launch
extern "C" void kernel_launch(void* const* d_in, const int* in_sizes, int n_in,
                              void* d_out, int out_size, void* d_ws, size_t ws_size,
                              hipStream_t stream) {
    const int*   X    = (const int*)d_in[0];
    const int*   erow = (const int*)d_in[1];
    const int*   ecol = (const int*)d_in[2];
    const float* emb  = (const float*)d_in[3];
    const float* q_w  = (const float*)d_in[4];
    const float* q_b  = (const float*)d_in[5];
    const float* k_w  = (const float*)d_in[6];
    const float* k_b  = (const float*)d_in[7];
    const float* v_w  = (const float*)d_in[8];
    const float* v_b  = (const float*)d_in[9];
    const float* o_w  = (const float*)d_in[10];
    const float* o_b  = (const float*)d_in[11];
    float* out = (float*)d_out;

    char* ws = (char*)d_ws;
    // layout (bytes):
    //   h / agg (aliased) : bf16 N*256       = 10,240,000  @ 0
    //   qhp               : bf16 4*N*64      = 10,240,000  @ 10,240,000
    //   kvhp              : bf16 4*N*128     = 20,480,000  @ 20,480,000
    //   wqkv              : bf16 768*256     =    393,216  @ 40,960,000
    //   wo                : bf16 256*256     =    131,072  @ 41,353,216
    //   qkvb              : fp32 768         =      3,072  @ 41,484,288
    //   row_ptr           : int (N+1)        =     80,004  @ 41,487,360
    bf16*   h    = (bf16*)(ws);
    bf16*   agg  = (bf16*)(ws);                 // aliases h (dead after QKV GEMM)
    ushort* qhp  = (ushort*)(ws + 10240000);
    ushort* kvhp = (ushort*)(ws + 20480000);
    bf16*   wqkv = (bf16*)(ws + 40960000);
    bf16*   wo   = (bf16*)(ws + 41353216);
    float*  qkvb = (float*)(ws + 41484288);
    int* row_ptr = (int*)(ws + 41487360);

    // fused pre-work: encode (5000) + weight prep (1027) + row_ptr (79)
    k_pre<<<6106, 256, 0, stream>>>(X, emb, h, q_w, k_w, v_w, o_w,
                                    q_b, k_b, v_b, wqkv, wo, qkvb, erow, row_ptr);

    // 1/sqrt(32) * log2(e): scores come out of the dot in log2 domain,
    // so k_attn uses raw v_exp_f32 (exp2) with no per-edge multiply.
    const float qscale = 0.25503486121587466f;
    dim3 gqkv((N_NODES + 127) / 128, 768 / 128);
    k_gemm_qkv<<<gqkv, 256, 0, stream>>>(h, wqkv, qkvb, qhp, kvhp, qscale);

    k_attn<<<N_NODES, 256, 0, stream>>>(row_ptr, ecol, qhp, kvhp, agg);

    dim3 go((N_NODES + 63) / 64, HIDDEN / 128);
    k_gemm_o<<<go, 256, 0, stream>>>(agg, wo, o_b, out);
}